// Round 4
// baseline (463.338 us; speedup 1.0000x reference)
//
#include <hip/hip_runtime.h>

#define H 128          // hidden dim (fixed by problem)
#define CAP 64         // max edges per (rel,dst) bucket

typedef _Float16 f16x8 __attribute__((ext_vector_type(8)));
typedef float    f32x4 __attribute__((ext_vector_type(4)));

// ---------------- edge bucketing: one pass, reused by both layers ----------------
__global__ __launch_bounds__(256) void hist_fill(const int* __restrict__ src,
    const int* __restrict__ dst, const int* __restrict__ et,
    int* __restrict__ cnt, int* __restrict__ elist, int E, int N)
{
    int e = blockIdx.x * 256 + threadIdx.x;
    if (e >= E) return;
    int s = src[e], d = dst[e], t = et[e];
    int b = t * N + d;
    int pos = atomicAdd(&cnt[b], 1);
    if (pos < CAP) elist[(size_t)b * CAP + pos] = s;
}

// ---------------- weight prep ----------------
// wInT: packed MFMA-B-fragment order: wpk[((k>>3)*H + c)*8 + (k&7)] = w_in[k*H+c]
// so a wave's B-frag load (lane l15=col, q=k-group) is 4x256B contiguous segments.
// w3T: plain [col][k] transpose (consumed from regs in gemm3, layout unchanged).
__global__ __launch_bounds__(256) void prep_w(const float* __restrict__ w_in,
    const float* __restrict__ w_root, const float* __restrict__ w_rel,
    _Float16* __restrict__ wInT, _Float16* __restrict__ w3T, int K)
{
    int idx = blockIdx.x * 256 + threadIdx.x;
    int tot1 = K * H;
    if (idx < tot1) {
        int k = idx >> 7, c = idx & 127;               // input order: coalesced read
        int o = ((k >> 3) << 10) + (c << 3) + (k & 7); // ((k/8)*H + c)*8 + k%8
        wInT[o] = (_Float16)w_in[idx];
    } else {
        int i2 = idx - tot1;
        if (i2 < 3 * H * H) {
            int m = i2 / (H * H), r2 = i2 - m * (H * H);
            int c = r2 >> 7, k = r2 & 127;
            const float* s = (m == 0) ? w_root : (w_rel + (size_t)(m - 1) * H * H);
            w3T[i2] = (_Float16)s[(size_t)k * H + c];
        }
    }
}

__device__ __forceinline__ f16x8 cvt8(float4 v0, float4 v1) {
    f16x8 t;
    t[0] = (_Float16)v0.x; t[1] = (_Float16)v0.y; t[2] = (_Float16)v0.z; t[3] = (_Float16)v0.w;
    t[4] = (_Float16)v1.x; t[5] = (_Float16)v1.y; t[6] = (_Float16)v1.z; t[7] = (_Float16)v1.w;
    return t;
}

// ---------------- big MFMA GEMM v3: 16-row waves + copy-free ping-pong -----------
// C16 = fp16(leakyrelu(A[M,768] @ W + b)). v2 post-mortem: 32-row waves gave only
// 1.5 blocks/CU (occupancy 13.4%) and the bf=nbf register copies forced a
// vmcnt(0) drain every K-step -> 24 serial latency exposures -> 95us @ 959GB/s.
// v3: (a) 16-row wave tiles -> 782 blocks = 12 waves/CU (3/SIMD), 2x TLP;
// (b) explicit 2-body unrolled loop with two NAMED operand sets and no inter-set
// copies -> compiler emits counted s_waitcnt vmcnt(N), ~20 loads in flight/wave.
// B re-read doubles (600MB L2 ~ 17us at 34.5TB/s) — acceptable, L1 absorbs part.
__global__ __launch_bounds__(256, 3) void gemm_big(const float* __restrict__ A,
    const _Float16* __restrict__ WP, const float* __restrict__ bias,
    _Float16* __restrict__ C16, int M, int K)
{
    const int tid = threadIdx.x;
    const int w   = tid >> 6;
    const int l   = tid & 63;
    const int l15 = l & 15;
    const int q   = l >> 4;
    const int wrow = blockIdx.x * 64 + w * 16;   // 16 rows per wave

    // A fragment row (lane l15 = row within the 16-row frag, q*8 = k offset)
    int r0 = wrow + l15; if (r0 >= M) r0 = M - 1;
    const float* ap = A + (size_t)r0 * K + q * 8;
    // packed B: step s, frag j -> WP + s*4096 + (q*H + j*16 + l15)*8
    const _Float16* bp = WP + ((size_t)q * H + l15) * 8;

    float bj[8];
#pragma unroll
    for (int j = 0; j < 8; j++) bj[j] = bias[j * 16 + l15];

    f32x4 acc[8];
    const f32x4 z4 = {0.f, 0.f, 0.f, 0.f};
#pragma unroll
    for (int j = 0; j < 8; j++) acc[j] = z4;

    // two named operand sets — NO copies between them (enables counted vmcnt)
    float4 aA0, aA1; f16x8 bA[8];
    float4 aB0, aB1; f16x8 bB[8];

    // prologue: set A <- step 0
    aA0 = *(const float4*)(ap);
    aA1 = *(const float4*)(ap + 4);
#pragma unroll
    for (int j = 0; j < 8; j++) bA[j] = *(const f16x8*)(bp + j * 128);

    const int steps = K / 32;                    // 24 (even)
    for (int s = 0; s < steps; s += 2) {
        // load set B <- step s+1 (always valid: steps even, s <= steps-2)
        {
            const int k1 = (s + 1) * 32;
            aB0 = *(const float4*)(ap + k1);
            aB1 = *(const float4*)(ap + k1 + 4);
            const _Float16* nb = bp + (size_t)(s + 1) * 4096;
#pragma unroll
            for (int j = 0; j < 8; j++) bB[j] = *(const f16x8*)(nb + j * 128);
        }
        // compute step s from set A
        {
            f16x8 af = cvt8(aA0, aA1);
#pragma unroll
            for (int j = 0; j < 8; j++)
                acc[j] = __builtin_amdgcn_mfma_f32_16x16x32_f16(af, bA[j], acc[j], 0, 0, 0);
        }
        // load set A <- step s+2 (skip on last pair)
        if (s + 2 < steps) {
            const int k2 = (s + 2) * 32;
            aA0 = *(const float4*)(ap + k2);
            aA1 = *(const float4*)(ap + k2 + 4);
            const _Float16* nb = bp + (size_t)(s + 2) * 4096;
#pragma unroll
            for (int j = 0; j < 8; j++) bA[j] = *(const f16x8*)(nb + j * 128);
        }
        // compute step s+1 from set B
        {
            f16x8 af = cvt8(aB0, aB1);
#pragma unroll
            for (int j = 0; j < 8; j++)
                acc[j] = __builtin_amdgcn_mfma_f32_16x16x32_f16(af, bB[j], acc[j], 0, 0, 0);
        }
    }

    // epilogue: bias + leaky, fp16 store (C frag: row = q*4+rg, col = j*16+l15)
#pragma unroll
    for (int rg = 0; rg < 4; rg++) {
        int row = wrow + q * 4 + rg;
        if (row < M) {
#pragma unroll
            for (int j = 0; j < 8; j++) {
                float v = acc[j][rg] + bj[j];
                v = (v >= 0.f) ? v : 0.01f * v;
                C16[(size_t)row * H + j * 16 + l15] = (_Float16)v;
            }
        }
    }
}

// ---------------- fused per-layer GEMM: B3 in regs, x software-pipelined ----------
// y = x@w_root + b (fp32); h_r = x@w_rel[r] (fp16). 512 threads = 8 waves x 16
// cols (full 128). Grid-stride over 16-row tiles; next tile's x-frags loaded
// before current tile's MFMAs (small reg arrays -> promoted).
__global__ __launch_bounds__(512) void gemm3(const _Float16* __restrict__ X16,
    const _Float16* __restrict__ W3, const float* __restrict__ bias,
    float* __restrict__ Y, _Float16* __restrict__ Hh, int M, int mtiles,
    size_t NH)
{
    const int w   = threadIdx.x >> 6;
    const int l   = threadIdx.x & 63;
    const int l15 = l & 15;
    const int q   = l >> 4;
    const int col = w * 16 + l15;

    f16x8 bf[3][4];
#pragma unroll
    for (int m = 0; m < 3; m++) {
        const _Float16* wpp = W3 + (size_t)m * H * H + (size_t)col * H + q * 8;
#pragma unroll
        for (int c = 0; c < 4; c++) bf[m][c] = *(const f16x8*)(wpp + c * 32);
    }
    const float bj = bias[col];

    int t = blockIdx.x;
    if (t >= mtiles) return;
    f16x8 xf[4];
    {
        const _Float16* xp = X16 + ((size_t)t * 16 + l15) * H + q * 8;
#pragma unroll
        for (int c = 0; c < 4; c++) xf[c] = *(const f16x8*)(xp + c * 32);
    }

    const f32x4 z4 = {0.f, 0.f, 0.f, 0.f};
    while (true) {
        int tn = t + gridDim.x;
        bool more = tn < mtiles;
        f16x8 xnf[4];
        if (more) {
            const _Float16* xp = X16 + ((size_t)tn * 16 + l15) * H + q * 8;
#pragma unroll
            for (int c = 0; c < 4; c++) xnf[c] = *(const f16x8*)(xp + c * 32);
        }

        f32x4 a0 = z4, a1 = z4, a2 = z4;
#pragma unroll
        for (int c = 0; c < 4; c++) {
            a0 = __builtin_amdgcn_mfma_f32_16x16x32_f16(xf[c], bf[0][c], a0, 0, 0, 0);
            a1 = __builtin_amdgcn_mfma_f32_16x16x32_f16(xf[c], bf[1][c], a1, 0, 0, 0);
            a2 = __builtin_amdgcn_mfma_f32_16x16x32_f16(xf[c], bf[2][c], a2, 0, 0, 0);
        }

#pragma unroll
        for (int rg = 0; rg < 4; rg++) {
            int row = t * 16 + q * 4 + rg;
            if (row < M) {
                Y [(size_t)row * H + col]      = a0[rg] + bj;
                Hh[(size_t)row * H + col]      = (_Float16)a1[rg];
                Hh[NH + (size_t)row * H + col] = (_Float16)a2[rg];
            }
        }
        if (!more) break;
        t = tn;
#pragma unroll
        for (int c = 0; c < 4; c++) xf[c] = xnf[c];
    }
}

// ---------------- mean-aggregate gather (+ optional fused output projection) ------
// xn[dst] = fp16( y[dst] + sum_r mean(h_r[src]) ). One wave per dst row.
// 4 edge slots x 16 col-lanes; per-lane DIRECT elist loads (same address within
// a slot group -> broadcast fetch; NO shfl in divergent flow — ds_bpermute
// returns 0 from inactive lanes, which silently corrupts. Learned round 6.)
// 4-deep unroll: four independent 16B h-row loads in flight (mean degree ~12 =>
// typical row is ONE L3 round trip instead of two).
// DO_OUT: instead of storing xn, fuse out[dst] = (y+agg) @ Wo + bo in-register
// (all lanes hold the reduced acc after the convergent xor-16/32 — project 8
// cols/lane, then convergent xor-1/2/4/8 over the 16 col groups). Kills the
// out_gemm kernel + 12.8MB xn write + 12.8MB re-read. OUT==3 assumed.
template<int DO_OUT>
__global__ __launch_bounds__(256) void gather_mean(const float* __restrict__ Y,
    const _Float16* __restrict__ h, const int* __restrict__ elist,
    const int* __restrict__ cnt, _Float16* __restrict__ xn, int N, size_t NH,
    const float* __restrict__ Wo, const float* __restrict__ bo,
    float* __restrict__ out)
{
    int wv = blockIdx.x * 4 + (threadIdx.x >> 6);
    int l  = threadIdx.x & 63;
    if (wv >= N) return;

    int d0r = cnt[wv], d1r = cnt[N + wv];
    int d0 = d0r < CAP ? d0r : CAP;
    int d1 = d1r < CAP ? d1r : CAP;
    float inv0 = d0r > 0 ? 1.f / (float)d0r : 0.f;
    float inv1 = d1r > 0 ? 1.f / (float)d1r : 0.f;
    const int* l0 = elist + (size_t)wv * CAP;
    const int* l1 = elist + ((size_t)N + wv) * CAP;
    const int tot = d0 + d1;

    const int eo = l >> 4;          // edge slot 0..3
    const int c8 = (l & 15) * 8;    // 8-col group

    // per-lane Wo rows (L1-hot broadcast across eo replicas) for fused projection
    float wo0[8], wo1[8], wo2[8];
    if (DO_OUT) {
#pragma unroll
        for (int j = 0; j < 8; j++) {
            wo0[j] = Wo[(c8 + j) * 3 + 0];
            wo1[j] = Wo[(c8 + j) * 3 + 1];
            wo2[j] = Wo[(c8 + j) * 3 + 2];
        }
    }

    float acc[8];
#pragma unroll
    for (int j = 0; j < 8; j++) acc[j] = 0.f;

    const f16x8 zv = {};
    for (int p = eo; p < tot; p += 16) {
        int p1 = p + 4, p2 = p + 8, p3 = p + 12;
        // slot 0 always valid
        bool fA = p < d0;
        int   sA  = fA ? l0[p] : l1[p - d0];
        float scA = fA ? inv0 : inv1;
        f16x8 vA  = *(const f16x8*)&h[(fA ? (size_t)0 : NH) + (size_t)sA * H + c8];
        f16x8 vB = zv, vC = zv, vD = zv;
        float scB = 0.f, scC = 0.f, scD = 0.f;
        if (p1 < tot) {
            bool f = p1 < d0;
            int s = f ? l0[p1] : l1[p1 - d0];
            scB = f ? inv0 : inv1;
            vB = *(const f16x8*)&h[(f ? (size_t)0 : NH) + (size_t)s * H + c8];
        }
        if (p2 < tot) {
            bool f = p2 < d0;
            int s = f ? l0[p2] : l1[p2 - d0];
            scC = f ? inv0 : inv1;
            vC = *(const f16x8*)&h[(f ? (size_t)0 : NH) + (size_t)s * H + c8];
        }
        if (p3 < tot) {
            bool f = p3 < d0;
            int s = f ? l0[p3] : l1[p3 - d0];
            scD = f ? inv0 : inv1;
            vD = *(const f16x8*)&h[(f ? (size_t)0 : NH) + (size_t)s * H + c8];
        }
#pragma unroll
        for (int j = 0; j < 8; j++)
            acc[j] += scA * (float)vA[j] + scB * (float)vB[j]
                    + scC * (float)vC[j] + scD * (float)vD[j];
    }

    // convergent full-wave reduction across the 4 edge slots
#pragma unroll
    for (int j = 0; j < 8; j++) {
        acc[j] += __shfl_xor(acc[j], 16);
        acc[j] += __shfl_xor(acc[j], 32);
    }

    // y add (all lanes: eo-replicated addresses -> broadcast fetch)
    float4 y0 = *(const float4*)&Y[(size_t)wv * H + c8];
    float4 y1 = *(const float4*)&Y[(size_t)wv * H + c8 + 4];
    float xv[8];
    xv[0] = acc[0] + y0.x; xv[1] = acc[1] + y0.y;
    xv[2] = acc[2] + y0.z; xv[3] = acc[3] + y0.w;
    xv[4] = acc[4] + y1.x; xv[5] = acc[5] + y1.y;
    xv[6] = acc[6] + y1.z; xv[7] = acc[7] + y1.w;

    if (DO_OUT) {
        float p0 = 0.f, p1 = 0.f, p2 = 0.f;
#pragma unroll
        for (int j = 0; j < 8; j++) {
            p0 += xv[j] * wo0[j];
            p1 += xv[j] * wo1[j];
            p2 += xv[j] * wo2[j];
        }
        // convergent reduction over the 16 col groups (bits 0..3 of lane)
#pragma unroll
        for (int off = 1; off <= 8; off <<= 1) {
            p0 += __shfl_xor(p0, off);
            p1 += __shfl_xor(p1, off);
            p2 += __shfl_xor(p2, off);
        }
        if (l == 0) {
            out[(size_t)wv * 3 + 0] = p0 + bo[0];
            out[(size_t)wv * 3 + 1] = p1 + bo[1];
            out[(size_t)wv * 3 + 2] = p2 + bo[2];
        }
    } else {
        if (eo == 0) {
            f16x8 o;
#pragma unroll
            for (int j = 0; j < 8; j++) o[j] = (_Float16)xv[j];
            *(f16x8*)&xn[(size_t)wv * H + c8] = o;
        }
    }
}

// ---------------- final projection (fallback when OUT != 3) ----------------------
__global__ __launch_bounds__(256) void out_gemm(const _Float16* __restrict__ X16,
    const float* __restrict__ Wo, const float* __restrict__ bo,
    float* __restrict__ out, int N, int OUT)
{
    int row = blockIdx.x * 4 + (threadIdx.x >> 6);
    int lane = threadIdx.x & 63;
    if (row >= N) return;
    float a0 = (float)X16[(size_t)row * H + lane];
    float a1 = (float)X16[(size_t)row * H + 64 + lane];
    for (int c = 0; c < OUT; c++) {
        float p = a0 * Wo[lane * OUT + c] + a1 * Wo[(64 + lane) * OUT + c];
        for (int off = 32; off > 0; off >>= 1) p += __shfl_down(p, off);
        if (lane == 0) out[(size_t)row * OUT + c] = p + bo[c];
    }
}

extern "C" void kernel_launch(void* const* d_in, const int* in_sizes, int n_in,
                              void* d_out, int out_size, void* d_ws, size_t ws_size,
                              hipStream_t stream) {
    const float* feature = (const float*)d_in[0];
    const int*   ei      = (const int*)d_in[1];   // [2,E]: src then dst
    const int*   et      = (const int*)d_in[2];   // [E]
    const float* w_in    = (const float*)d_in[3];
    const float* b_in    = (const float*)d_in[4];
    const float* w_rel   = (const float*)d_in[5];
    const float* w_root  = (const float*)d_in[6];
    const float* b_conv  = (const float*)d_in[7];
    const float* w_out   = (const float*)d_in[8];
    const float* b_out   = (const float*)d_in[9];

    const int HH   = in_sizes[4];                 // 128
    const int D_IN = in_sizes[3] / HH;            // 768
    const int N    = in_sizes[0] / D_IN;          // 50000
    const int E    = in_sizes[1] / 2;             // 600000
    const int R    = in_sizes[5] / (HH * HH);     // 2 (layout assumes 2)
    const int OUT  = in_sizes[9];                 // 3

    const size_t NH = (size_t)N * H;

    // workspace layout (16B-aligned segments)
    char* base = (char*)d_ws;
    _Float16* wInT = (_Float16*)base;                              // 128*K (packed)
    _Float16* w3T  = wInT + (size_t)D_IN * HH;                     // 3*128*128
    _Float16* x0   = w3T + (size_t)3 * HH * HH;                    // N*H fp16
    _Float16* x1   = x0 + NH;                                      // N*H fp16
    _Float16* h    = x1 + NH;                                      // R*N*H fp16
    float* y       = (float*)(h + (size_t)R * NH);                 // N*H fp32
    int* cnt       = (int*)(y + NH);                               // R*N
    int* elist     = cnt + (size_t)R * N;                          // R*N*CAP

    hipMemsetAsync(cnt, 0, sizeof(int) * (size_t)R * N, stream);
    prep_w<<<(D_IN * HH + 3 * HH * HH + 255) / 256, 256, 0, stream>>>(
        w_in, w_root, w_rel, wInT, w3T, D_IN);
    hist_fill<<<(E + 255) / 256, 256, 0, stream>>>(ei, ei + E, et, cnt, elist, E, N);

    // x0 = fp16(leakyrelu(feature @ w_in + b_in)) — 16-row-wave streaming GEMM
    gemm_big<<<(N + 63) / 64, 256, 0, stream>>>(feature, wInT, b_in, x0, N, D_IN);

    const int mtiles = (N + 15) / 16;             // 3125 exact for N=50000
    const int gblocks = (N + 3) / 4;

    // layer 1
    gemm3<<<1024, 512, 0, stream>>>(x0, w3T, b_conv, y, h, N, mtiles, NH);
    gather_mean<0><<<gblocks, 256, 0, stream>>>(y, h, elist, cnt, x1, N, NH,
                                                nullptr, nullptr, nullptr);
    // layer 2 (+ fused output projection when OUT==3)
    gemm3<<<1024, 512, 0, stream>>>(x1, w3T, b_conv, y, h, N, mtiles, NH);
    if (OUT == 3) {
        gather_mean<1><<<gblocks, 256, 0, stream>>>(y, h, elist, cnt, x0, N, NH,
                                                    w_out, b_out, (float*)d_out);
    } else {
        gather_mean<0><<<gblocks, 256, 0, stream>>>(y, h, elist, cnt, x0, N, NH,
                                                    nullptr, nullptr, nullptr);
        out_gemm<<<gblocks, 256, 0, stream>>>(x0, w_out, b_out, (float*)d_out, N, OUT);
    }
}

// Round 5
// 452.100 us; speedup vs baseline: 1.0249x; 1.0249x over previous
//
#include <hip/hip_runtime.h>

#define H 128          // hidden dim (fixed by problem)
#define CAP 64         // max edges per (rel,dst) bucket

typedef _Float16 f16x8 __attribute__((ext_vector_type(8)));
typedef _Float16 f16x4 __attribute__((ext_vector_type(4)));
typedef float    f32x4 __attribute__((ext_vector_type(4)));

// ---------------- edge bucketing: one pass, reused by both layers ----------------
__global__ __launch_bounds__(256) void hist_fill(const int* __restrict__ src,
    const int* __restrict__ dst, const int* __restrict__ et,
    int* __restrict__ cnt, int* __restrict__ elist, int E, int N)
{
    int e = blockIdx.x * 256 + threadIdx.x;
    if (e >= E) return;
    int s = src[e], d = dst[e], t = et[e];
    int b = t * N + d;
    int pos = atomicAdd(&cnt[b], 1);
    if (pos < CAP) elist[(size_t)b * CAP + pos] = s;
}

// ---------------- weight prep ----------------
// wInT: packed MFMA-B-fragment order: wpk[((k>>3)*H + c)*8 + (k&7)] = w_in[k*H+c]
// so a wave's B-frag load (lane l15=col, q=k-group) is 4x256B contiguous segments.
// w3T: plain [col][k] transpose (consumed from regs in gemm3, layout unchanged).
__global__ __launch_bounds__(256) void prep_w(const float* __restrict__ w_in,
    const float* __restrict__ w_root, const float* __restrict__ w_rel,
    _Float16* __restrict__ wInT, _Float16* __restrict__ w3T, int K)
{
    int idx = blockIdx.x * 256 + threadIdx.x;
    int tot1 = K * H;
    if (idx < tot1) {
        int k = idx >> 7, c = idx & 127;               // input order: coalesced read
        int o = ((k >> 3) << 10) + (c << 3) + (k & 7); // ((k/8)*H + c)*8 + k%8
        wInT[o] = (_Float16)w_in[idx];
    } else {
        int i2 = idx - tot1;
        if (i2 < 3 * H * H) {
            int m = i2 / (H * H), r2 = i2 - m * (H * H);
            int c = r2 >> 7, k = r2 & 127;
            const float* s = (m == 0) ? w_root : (w_rel + (size_t)(m - 1) * H * H);
            w3T[i2] = (_Float16)s[(size_t)k * H + c];
        }
    }
}

// ---------------- big MFMA GEMM v4: contiguous-run LDS staging -------------------
// C16 = fp16(leakyrelu(A[M,768] @ W + b)).
// Post-mortem r0-r4: THREE structures (LDS-dbuf, 32-row reg-stream, 16-row
// ping-pong) all stuck at ~95-103us / ~900GB/s with all pipes idle. Common
// factor: A-fragment loads fetch 16 rows x 64-128B at 3KB stride per wave
// instruction -> DRAM sees scattered short runs -> ~7x service-rate loss
// (fillBuffer streams 6.4TB/s on the same chip; run length is the difference).
// v4: per 128-k chunk, each wave reads its 16 rows as CONTIGUOUS 512B runs
// (2 rows per 1KB lane-consecutive load), cvt fp32->f16 in regs, ds_write into
// fragment-packed LDS [slot=k/8][row^(slot&7)][8] (XOR -> write 4dw/bank floor,
// read b128 8dw/bank floor, q drops out of bank index). Double-buffered, ONE
// barrier per chunk; next chunk's 8 loads issue before compute so HBM latency
// hides under 32 MFMAs x 3 blocks/CU.
__global__ __launch_bounds__(256, 3) void gemm_big(const float* __restrict__ A,
    const _Float16* __restrict__ WP, const float* __restrict__ bias,
    _Float16* __restrict__ C16, int M, int K)
{
    __shared__ _Float16 As[2][8192];   // [buf][slot*512 + (row^(slot&7))*8 + e]

    const int tid = threadIdx.x;
    const int w   = tid >> 6;
    const int l   = tid & 63;
    const int l15 = l & 15;
    const int q   = l >> 4;
    const int brow = blockIdx.x * 64;
    const int wr   = w * 16;                    // wave's 16-row slice of the tile

    // staging geometry (constant per thread)
    const int srow = wr + (l >> 5);             // + i*2 per iter -> rows wr..wr+15
    const int sk4  = (l & 31) * 4;              // k offset within chunk (floats)
    const int slot = (l & 31) >> 1;             // k/8 within chunk
    const int half = l & 1;                     // which 4-f16 half of the slot

    // packed B: step s(32k), frag j -> WP + s*4096 + (q*H + j*16 + l15)*8
    const _Float16* bp = WP + ((size_t)q * H + l15) * 8;

    float bj[8];
#pragma unroll
    for (int j = 0; j < 8; j++) bj[j] = bias[j * 16 + l15];

    f32x4 acc[8];
    const f32x4 z4 = {0.f, 0.f, 0.f, 0.f};
#pragma unroll
    for (int j = 0; j < 8; j++) acc[j] = z4;

    const int chunks = K / 128;                 // 6
    float4 st[8];

    // ---- prologue: stage chunk 0 ----
    {
        const float* apc = A + sk4;
#pragma unroll
        for (int i = 0; i < 8; i++) {
            int gr = brow + srow + i * 2; if (gr >= M) gr = M - 1;
            st[i] = *(const float4*)(apc + (size_t)gr * K);
        }
#pragma unroll
        for (int i = 0; i < 8; i++) {
            int row = srow + i * 2;
            int idx = slot * 512 + ((row ^ (slot & 7)) << 3) + half * 4;
            f16x4 v; v[0] = (_Float16)st[i].x; v[1] = (_Float16)st[i].y;
                     v[2] = (_Float16)st[i].z; v[3] = (_Float16)st[i].w;
            *(f16x4*)&As[0][idx] = v;
        }
    }
    __syncthreads();

    for (int c = 0; c < chunks; c++) {
        const bool more = (c + 1) < chunks;
        // issue next chunk's 8 contiguous loads (in flight during compute)
        if (more) {
            const float* apc = A + (c + 1) * 128 + sk4;
#pragma unroll
            for (int i = 0; i < 8; i++) {
                int gr = brow + srow + i * 2; if (gr >= M) gr = M - 1;
                st[i] = *(const float4*)(apc + (size_t)gr * K);
            }
        }
        // compute chunk c from LDS buffer (c&1): 4 ks-steps x 8 MFMA
        {
            const _Float16* __restrict__ buf = As[c & 1];
#pragma unroll
            for (int ks = 0; ks < 4; ks++) {
                const int sl = ks * 4 + q;
                f16x8 af = *(const f16x8*)&buf[sl * 512 + (((wr + l15) ^ (sl & 7)) << 3)];
                const _Float16* bks = bp + (size_t)(c * 4 + ks) * 4096;
                f16x8 bf[8];
#pragma unroll
                for (int j = 0; j < 8; j++) bf[j] = *(const f16x8*)(bks + j * 128);
#pragma unroll
                for (int j = 0; j < 8; j++)
                    acc[j] = __builtin_amdgcn_mfma_f32_16x16x32_f16(af, bf[j], acc[j], 0, 0, 0);
            }
        }
        // write next chunk to the other buffer (counted vmcnt on the st loads)
        if (more) {
            _Float16* __restrict__ buf = As[(c + 1) & 1];
#pragma unroll
            for (int i = 0; i < 8; i++) {
                int row = srow + i * 2;
                int idx = slot * 512 + ((row ^ (slot & 7)) << 3) + half * 4;
                f16x4 v; v[0] = (_Float16)st[i].x; v[1] = (_Float16)st[i].y;
                         v[2] = (_Float16)st[i].z; v[3] = (_Float16)st[i].w;
                *(f16x4*)&buf[idx] = v;
            }
        }
        __syncthreads();
    }

    // epilogue: bias + leaky, fp16 store (C frag: row = q*4+rg, col = j*16+l15)
#pragma unroll
    for (int rg = 0; rg < 4; rg++) {
        int row = brow + wr + q * 4 + rg;
        if (row < M) {
#pragma unroll
            for (int j = 0; j < 8; j++) {
                float v = acc[j][rg] + bj[j];
                v = (v >= 0.f) ? v : 0.01f * v;
                C16[(size_t)row * H + j * 16 + l15] = (_Float16)v;
            }
        }
    }
}

// ---------------- fused per-layer GEMM: B3 in regs, x software-pipelined ----------
// y = x@w_root + b (fp32); h_r = x@w_rel[r] (fp16). 512 threads = 8 waves x 16
// cols (full 128). Grid-stride over 16-row tiles; next tile's x-frags loaded
// before current tile's MFMAs (small reg arrays -> promoted).
__global__ __launch_bounds__(512) void gemm3(const _Float16* __restrict__ X16,
    const _Float16* __restrict__ W3, const float* __restrict__ bias,
    float* __restrict__ Y, _Float16* __restrict__ Hh, int M, int mtiles,
    size_t NH)
{
    const int w   = threadIdx.x >> 6;
    const int l   = threadIdx.x & 63;
    const int l15 = l & 15;
    const int q   = l >> 4;
    const int col = w * 16 + l15;

    f16x8 bf[3][4];
#pragma unroll
    for (int m = 0; m < 3; m++) {
        const _Float16* wpp = W3 + (size_t)m * H * H + (size_t)col * H + q * 8;
#pragma unroll
        for (int c = 0; c < 4; c++) bf[m][c] = *(const f16x8*)(wpp + c * 32);
    }
    const float bj = bias[col];

    int t = blockIdx.x;
    if (t >= mtiles) return;
    f16x8 xf[4];
    {
        const _Float16* xp = X16 + ((size_t)t * 16 + l15) * H + q * 8;
#pragma unroll
        for (int c = 0; c < 4; c++) xf[c] = *(const f16x8*)(xp + c * 32);
    }

    const f32x4 z4 = {0.f, 0.f, 0.f, 0.f};
    while (true) {
        int tn = t + gridDim.x;
        bool more = tn < mtiles;
        f16x8 xnf[4];
        if (more) {
            const _Float16* xp = X16 + ((size_t)tn * 16 + l15) * H + q * 8;
#pragma unroll
            for (int c = 0; c < 4; c++) xnf[c] = *(const f16x8*)(xp + c * 32);
        }

        f32x4 a0 = z4, a1 = z4, a2 = z4;
#pragma unroll
        for (int c = 0; c < 4; c++) {
            a0 = __builtin_amdgcn_mfma_f32_16x16x32_f16(xf[c], bf[0][c], a0, 0, 0, 0);
            a1 = __builtin_amdgcn_mfma_f32_16x16x32_f16(xf[c], bf[1][c], a1, 0, 0, 0);
            a2 = __builtin_amdgcn_mfma_f32_16x16x32_f16(xf[c], bf[2][c], a2, 0, 0, 0);
        }

#pragma unroll
        for (int rg = 0; rg < 4; rg++) {
            int row = t * 16 + q * 4 + rg;
            if (row < M) {
                Y [(size_t)row * H + col]      = a0[rg] + bj;
                Hh[(size_t)row * H + col]      = (_Float16)a1[rg];
                Hh[NH + (size_t)row * H + col] = (_Float16)a2[rg];
            }
        }
        if (!more) break;
        t = tn;
#pragma unroll
        for (int c = 0; c < 4; c++) xf[c] = xnf[c];
    }
}

// ---------------- mean-aggregate gather (+ optional fused output projection) ------
// xn[dst] = fp16( y[dst] + sum_r mean(h_r[src]) ). One wave per dst row.
// 4 edge slots x 16 col-lanes; per-lane DIRECT elist loads (same address within
// a slot group -> broadcast fetch; NO shfl in divergent flow — ds_bpermute
// returns 0 from inactive lanes, which silently corrupts. Learned round 6.)
// 4-deep unroll: four independent 16B h-row loads in flight (mean degree ~12 =>
// typical row is ONE L3 round trip instead of two).
// DO_OUT: instead of storing xn, fuse out[dst] = (y+agg) @ Wo + bo in-register
// (all lanes hold the reduced acc after the convergent xor-16/32 — project 8
// cols/lane, then convergent xor-1/2/4/8 over the 16 col groups). Kills the
// out_gemm kernel + 12.8MB xn write + 12.8MB re-read. OUT==3 assumed.
template<int DO_OUT>
__global__ __launch_bounds__(256) void gather_mean(const float* __restrict__ Y,
    const _Float16* __restrict__ h, const int* __restrict__ elist,
    const int* __restrict__ cnt, _Float16* __restrict__ xn, int N, size_t NH,
    const float* __restrict__ Wo, const float* __restrict__ bo,
    float* __restrict__ out)
{
    int wv = blockIdx.x * 4 + (threadIdx.x >> 6);
    int l  = threadIdx.x & 63;
    if (wv >= N) return;

    int d0r = cnt[wv], d1r = cnt[N + wv];
    int d0 = d0r < CAP ? d0r : CAP;
    int d1 = d1r < CAP ? d1r : CAP;
    float inv0 = d0r > 0 ? 1.f / (float)d0r : 0.f;
    float inv1 = d1r > 0 ? 1.f / (float)d1r : 0.f;
    const int* l0 = elist + (size_t)wv * CAP;
    const int* l1 = elist + ((size_t)N + wv) * CAP;
    const int tot = d0 + d1;

    const int eo = l >> 4;          // edge slot 0..3
    const int c8 = (l & 15) * 8;    // 8-col group

    // per-lane Wo rows (L1-hot broadcast across eo replicas) for fused projection
    float wo0[8], wo1[8], wo2[8];
    if (DO_OUT) {
#pragma unroll
        for (int j = 0; j < 8; j++) {
            wo0[j] = Wo[(c8 + j) * 3 + 0];
            wo1[j] = Wo[(c8 + j) * 3 + 1];
            wo2[j] = Wo[(c8 + j) * 3 + 2];
        }
    }

    float acc[8];
#pragma unroll
    for (int j = 0; j < 8; j++) acc[j] = 0.f;

    const f16x8 zv = {};
    for (int p = eo; p < tot; p += 16) {
        int p1 = p + 4, p2 = p + 8, p3 = p + 12;
        // slot 0 always valid
        bool fA = p < d0;
        int   sA  = fA ? l0[p] : l1[p - d0];
        float scA = fA ? inv0 : inv1;
        f16x8 vA  = *(const f16x8*)&h[(fA ? (size_t)0 : NH) + (size_t)sA * H + c8];
        f16x8 vB = zv, vC = zv, vD = zv;
        float scB = 0.f, scC = 0.f, scD = 0.f;
        if (p1 < tot) {
            bool f = p1 < d0;
            int s = f ? l0[p1] : l1[p1 - d0];
            scB = f ? inv0 : inv1;
            vB = *(const f16x8*)&h[(f ? (size_t)0 : NH) + (size_t)s * H + c8];
        }
        if (p2 < tot) {
            bool f = p2 < d0;
            int s = f ? l0[p2] : l1[p2 - d0];
            scC = f ? inv0 : inv1;
            vC = *(const f16x8*)&h[(f ? (size_t)0 : NH) + (size_t)s * H + c8];
        }
        if (p3 < tot) {
            bool f = p3 < d0;
            int s = f ? l0[p3] : l1[p3 - d0];
            scD = f ? inv0 : inv1;
            vD = *(const f16x8*)&h[(f ? (size_t)0 : NH) + (size_t)s * H + c8];
        }
#pragma unroll
        for (int j = 0; j < 8; j++)
            acc[j] += scA * (float)vA[j] + scB * (float)vB[j]
                    + scC * (float)vC[j] + scD * (float)vD[j];
    }

    // convergent full-wave reduction across the 4 edge slots
#pragma unroll
    for (int j = 0; j < 8; j++) {
        acc[j] += __shfl_xor(acc[j], 16);
        acc[j] += __shfl_xor(acc[j], 32);
    }

    // y add (all lanes: eo-replicated addresses -> broadcast fetch)
    float4 y0 = *(const float4*)&Y[(size_t)wv * H + c8];
    float4 y1 = *(const float4*)&Y[(size_t)wv * H + c8 + 4];
    float xv[8];
    xv[0] = acc[0] + y0.x; xv[1] = acc[1] + y0.y;
    xv[2] = acc[2] + y0.z; xv[3] = acc[3] + y0.w;
    xv[4] = acc[4] + y1.x; xv[5] = acc[5] + y1.y;
    xv[6] = acc[6] + y1.z; xv[7] = acc[7] + y1.w;

    if (DO_OUT) {
        float p0 = 0.f, p1 = 0.f, p2 = 0.f;
#pragma unroll
        for (int j = 0; j < 8; j++) {
            p0 += xv[j] * wo0[j];
            p1 += xv[j] * wo1[j];
            p2 += xv[j] * wo2[j];
        }
        // convergent reduction over the 16 col groups (bits 0..3 of lane)
#pragma unroll
        for (int off = 1; off <= 8; off <<= 1) {
            p0 += __shfl_xor(p0, off);
            p1 += __shfl_xor(p1, off);
            p2 += __shfl_xor(p2, off);
        }
        if (l == 0) {
            out[(size_t)wv * 3 + 0] = p0 + bo[0];
            out[(size_t)wv * 3 + 1] = p1 + bo[1];
            out[(size_t)wv * 3 + 2] = p2 + bo[2];
        }
    } else {
        if (eo == 0) {
            f16x8 o;
#pragma unroll
            for (int j = 0; j < 8; j++) o[j] = (_Float16)xv[j];
            *(f16x8*)&xn[(size_t)wv * H + c8] = o;
        }
    }
}

// ---------------- final projection (fallback when OUT != 3) ----------------------
__global__ __launch_bounds__(256) void out_gemm(const _Float16* __restrict__ X16,
    const float* __restrict__ Wo, const float* __restrict__ bo,
    float* __restrict__ out, int N, int OUT)
{
    int row = blockIdx.x * 4 + (threadIdx.x >> 6);
    int lane = threadIdx.x & 63;
    if (row >= N) return;
    float a0 = (float)X16[(size_t)row * H + lane];
    float a1 = (float)X16[(size_t)row * H + 64 + lane];
    for (int c = 0; c < OUT; c++) {
        float p = a0 * Wo[lane * OUT + c] + a1 * Wo[(64 + lane) * OUT + c];
        for (int off = 32; off > 0; off >>= 1) p += __shfl_down(p, off);
        if (lane == 0) out[(size_t)row * OUT + c] = p + bo[c];
    }
}

extern "C" void kernel_launch(void* const* d_in, const int* in_sizes, int n_in,
                              void* d_out, int out_size, void* d_ws, size_t ws_size,
                              hipStream_t stream) {
    const float* feature = (const float*)d_in[0];
    const int*   ei      = (const int*)d_in[1];   // [2,E]: src then dst
    const int*   et      = (const int*)d_in[2];   // [E]
    const float* w_in    = (const float*)d_in[3];
    const float* b_in    = (const float*)d_in[4];
    const float* w_rel   = (const float*)d_in[5];
    const float* w_root  = (const float*)d_in[6];
    const float* b_conv  = (const float*)d_in[7];
    const float* w_out   = (const float*)d_in[8];
    const float* b_out   = (const float*)d_in[9];

    const int HH   = in_sizes[4];                 // 128
    const int D_IN = in_sizes[3] / HH;            // 768
    const int N    = in_sizes[0] / D_IN;          // 50000
    const int E    = in_sizes[1] / 2;             // 600000
    const int R    = in_sizes[5] / (HH * HH);     // 2 (layout assumes 2)
    const int OUT  = in_sizes[9];                 // 3

    const size_t NH = (size_t)N * H;

    // workspace layout (16B-aligned segments)
    char* base = (char*)d_ws;
    _Float16* wInT = (_Float16*)base;                              // 128*K (packed)
    _Float16* w3T  = wInT + (size_t)D_IN * HH;                     // 3*128*128
    _Float16* x0   = w3T + (size_t)3 * HH * HH;                    // N*H fp16
    _Float16* x1   = x0 + NH;                                      // N*H fp16
    _Float16* h    = x1 + NH;                                      // R*N*H fp16
    float* y       = (float*)(h + (size_t)R * NH);                 // N*H fp32
    int* cnt       = (int*)(y + NH);                               // R*N
    int* elist     = cnt + (size_t)R * N;                          // R*N*CAP

    hipMemsetAsync(cnt, 0, sizeof(int) * (size_t)R * N, stream);
    prep_w<<<(D_IN * HH + 3 * HH * HH + 255) / 256, 256, 0, stream>>>(
        w_in, w_root, w_rel, wInT, w3T, D_IN);
    hist_fill<<<(E + 255) / 256, 256, 0, stream>>>(ei, ei + E, et, cnt, elist, E, N);

    // x0 = fp16(leakyrelu(feature @ w_in + b_in)) — contiguous-run LDS-staged GEMM
    gemm_big<<<(N + 63) / 64, 256, 0, stream>>>(feature, wInT, b_in, x0, N, D_IN);

    const int mtiles = (N + 15) / 16;             // 3125 exact for N=50000
    const int gblocks = (N + 3) / 4;

    // layer 1
    gemm3<<<1024, 512, 0, stream>>>(x0, w3T, b_conv, y, h, N, mtiles, NH);
    gather_mean<0><<<gblocks, 256, 0, stream>>>(y, h, elist, cnt, x1, N, NH,
                                                nullptr, nullptr, nullptr);
    // layer 2 (+ fused output projection when OUT==3)
    gemm3<<<1024, 512, 0, stream>>>(x1, w3T, b_conv, y, h, N, mtiles, NH);
    if (OUT == 3) {
        gather_mean<1><<<gblocks, 256, 0, stream>>>(y, h, elist, cnt, x0, N, NH,
                                                    w_out, b_out, (float*)d_out);
    } else {
        gather_mean<0><<<gblocks, 256, 0, stream>>>(y, h, elist, cnt, x0, N, NH,
                                                    nullptr, nullptr, nullptr);
        out_gemm<<<gblocks, 256, 0, stream>>>(x0, w_out, b_out, (float*)d_out, N, OUT);
    }
}

// Round 6
// 449.198 us; speedup vs baseline: 1.0315x; 1.0065x over previous
//
#include <hip/hip_runtime.h>

#define H 128          // hidden dim (fixed by problem)
#define CAP 64         // max edges per (rel,dst) bucket

typedef _Float16 f16x8 __attribute__((ext_vector_type(8)));
typedef _Float16 f16x4 __attribute__((ext_vector_type(4)));
typedef float    f32x4 __attribute__((ext_vector_type(4)));

// ---------------- edge bucketing: one pass, reused by both layers ----------------
__global__ __launch_bounds__(256) void hist_fill(const int* __restrict__ src,
    const int* __restrict__ dst, const int* __restrict__ et,
    int* __restrict__ cnt, int* __restrict__ elist, int E, int N)
{
    int e = blockIdx.x * 256 + threadIdx.x;
    if (e >= E) return;
    int s = src[e], d = dst[e], t = et[e];
    int b = t * N + d;
    int pos = atomicAdd(&cnt[b], 1);
    if (pos < CAP) elist[(size_t)b * CAP + pos] = s;
}

// ---------------- weight prep ----------------
// wInT: packed MFMA-B-fragment order for gemm_big (proven layout).
// wcatT: [col][384] f16 = concat_k(W_root;W_0;W_1) transposed — B for gemm_cat.
__global__ __launch_bounds__(256) void prep_w(const float* __restrict__ w_in,
    const float* __restrict__ w_root, const float* __restrict__ w_rel,
    _Float16* __restrict__ wInT, _Float16* __restrict__ wcatT, int K)
{
    int idx = blockIdx.x * 256 + threadIdx.x;
    int tot1 = K * H;                                  // 98304
    if (idx < tot1) {
        int k = idx >> 7, c = idx & 127;               // coalesced read of w_in
        int o = ((k >> 3) << 10) + (c << 3) + (k & 7); // ((k/8)*H + c)*8 + k%8
        wInT[o] = (_Float16)w_in[idx];
    } else {
        int i2 = idx - tot1;                           // < 128*384 = 49152
        if (i2 < H * 384) {
            int c = i2 / 384, k = i2 - c * 384;
            float v;
            if (k < 128)      v = w_root[(size_t)k * H + c];
            else if (k < 256) v = w_rel[(size_t)(k - 128) * H + c];
            else              v = w_rel[(size_t)H * H + (size_t)(k - 256) * H + c];
            wcatT[i2] = (_Float16)v;
        }
    }
}

// wfin[m][k][c] (m: 0=x,1=rel0,2=rel1; fp32) = W_m @ w_out ; bfin = b_conv@Wo + bo.
// Folds layer-2's dense GEMM + output projection into one [384,OUT] matrix.
__global__ __launch_bounds__(256) void prep_fin(const float* __restrict__ w_root,
    const float* __restrict__ w_rel, const float* __restrict__ b_conv,
    const float* __restrict__ w_out, const float* __restrict__ b_out,
    float* __restrict__ wfin, float* __restrict__ bfin, int OUT)
{
    int idx = blockIdx.x * 256 + threadIdx.x;
    if (idx < 3 * H) {
        int m = idx >> 7, k = idx & 127;
        const float* W = (m == 0) ? w_root : (w_rel + (size_t)(m - 1) * H * H);
        for (int c = 0; c < OUT; c++) {
            float s = 0.f;
            for (int j = 0; j < H; j++) s += W[(size_t)k * H + j] * w_out[(size_t)j * OUT + c];
            wfin[((size_t)m * H + k) * OUT + c] = s;
        }
    } else if (idx < 3 * H + OUT) {
        int c = idx - 3 * H;
        float s = b_out[c];
        for (int j = 0; j < H; j++) s += b_conv[j] * w_out[(size_t)j * OUT + c];
        bfin[c] = s;
    }
}

// ---------------- big MFMA GEMM (v4, unchanged structure): LDS contiguous staging --
// x1 = fp16(leakyrelu(feature@W_in + b_in)) written into XC[:,0:128] (ldc=384).
// NOTE r0-r5: four structures all ~94-103us; wall unexplained; parked.
__global__ __launch_bounds__(256, 3) void gemm_big(const float* __restrict__ A,
    const _Float16* __restrict__ WP, const float* __restrict__ bias,
    _Float16* __restrict__ C16, int M, int K, int ldc)
{
    __shared__ _Float16 As[2][8192];   // [buf][slot*512 + (row^(slot&7))*8 + e]

    const int tid = threadIdx.x;
    const int w   = tid >> 6;
    const int l   = tid & 63;
    const int l15 = l & 15;
    const int q   = l >> 4;
    const int brow = blockIdx.x * 64;
    const int wr   = w * 16;

    const int srow = wr + (l >> 5);
    const int sk4  = (l & 31) * 4;
    const int slot = (l & 31) >> 1;
    const int half = l & 1;

    const _Float16* bp = WP + ((size_t)q * H + l15) * 8;

    float bj[8];
#pragma unroll
    for (int j = 0; j < 8; j++) bj[j] = bias[j * 16 + l15];

    f32x4 acc[8];
    const f32x4 z4 = {0.f, 0.f, 0.f, 0.f};
#pragma unroll
    for (int j = 0; j < 8; j++) acc[j] = z4;

    const int chunks = K / 128;                 // 6
    float4 st[8];

    {
        const float* apc = A + sk4;
#pragma unroll
        for (int i = 0; i < 8; i++) {
            int gr = brow + srow + i * 2; if (gr >= M) gr = M - 1;
            st[i] = *(const float4*)(apc + (size_t)gr * K);
        }
#pragma unroll
        for (int i = 0; i < 8; i++) {
            int row = srow + i * 2;
            int idx = slot * 512 + ((row ^ (slot & 7)) << 3) + half * 4;
            f16x4 v; v[0] = (_Float16)st[i].x; v[1] = (_Float16)st[i].y;
                     v[2] = (_Float16)st[i].z; v[3] = (_Float16)st[i].w;
            *(f16x4*)&As[0][idx] = v;
        }
    }
    __syncthreads();

    for (int c = 0; c < chunks; c++) {
        const bool more = (c + 1) < chunks;
        if (more) {
            const float* apc = A + (c + 1) * 128 + sk4;
#pragma unroll
            for (int i = 0; i < 8; i++) {
                int gr = brow + srow + i * 2; if (gr >= M) gr = M - 1;
                st[i] = *(const float4*)(apc + (size_t)gr * K);
            }
        }
        {
            const _Float16* __restrict__ buf = As[c & 1];
#pragma unroll
            for (int ks = 0; ks < 4; ks++) {
                const int sl = ks * 4 + q;
                f16x8 af = *(const f16x8*)&buf[sl * 512 + (((wr + l15) ^ (sl & 7)) << 3)];
                const _Float16* bks = bp + (size_t)(c * 4 + ks) * 4096;
                f16x8 bf[8];
#pragma unroll
                for (int j = 0; j < 8; j++) bf[j] = *(const f16x8*)(bks + j * 128);
#pragma unroll
                for (int j = 0; j < 8; j++)
                    acc[j] = __builtin_amdgcn_mfma_f32_16x16x32_f16(af, bf[j], acc[j], 0, 0, 0);
            }
        }
        if (more) {
            _Float16* __restrict__ buf = As[(c + 1) & 1];
#pragma unroll
            for (int i = 0; i < 8; i++) {
                int row = srow + i * 2;
                int idx = slot * 512 + ((row ^ (slot & 7)) << 3) + half * 4;
                f16x4 v; v[0] = (_Float16)st[i].x; v[1] = (_Float16)st[i].y;
                         v[2] = (_Float16)st[i].z; v[3] = (_Float16)st[i].w;
                *(f16x4*)&buf[idx] = v;
            }
        }
        __syncthreads();
    }

#pragma unroll
    for (int rg = 0; rg < 4; rg++) {
        int row = brow + wr + q * 4 + rg;
        if (row < M) {
#pragma unroll
            for (int j = 0; j < 8; j++) {
                float v = acc[j][rg] + bj[j];
                v = (v >= 0.f) ? v : 0.01f * v;
                C16[(size_t)row * ldc + j * 16 + l15] = (_Float16)v;
            }
        }
    }
}

// ---------------- raw-x gather (mean commutes with the relation GEMM) -------------
// MODE 0: m_r[dst] = mean_{N_r(dst)} x[src]; write fp16 into XC[:,128+r*128].
// MODE 1: fused final layer: out[dst] = x[dst]@Wfin_x + sum_r m_r@Wfin_r + bfin
//         (means stay fp32 in registers; only 3 floats written per row).
// Lane layout: half = l>>5 selects relation; e2 = (l>>4)&1 is the 2-slot depth
// within the half; c8 = (l&15)*8 covers the 128 cols. 4-deep unroll per slot
// -> 16 independent 16B row-loads in flight per wave. shfl_xor(16) merges the
// two slot copies (convergent). NO shfl in divergent flow (learned rule).
template<int MODE>
__global__ __launch_bounds__(256) void gather_k(const _Float16* __restrict__ X,
    int ldx, _Float16* __restrict__ Mout, const int* __restrict__ elist,
    const int* __restrict__ cnt, int N,
    const float* __restrict__ wfin, const float* __restrict__ bfin,
    float* __restrict__ out)
{
    int wv = blockIdx.x * 4 + (threadIdx.x >> 6);
    int l  = threadIdx.x & 63;
    if (wv >= N) return;

    const int eo   = l >> 4;
    const int e2   = eo & 1;
    const int half = l >> 5;              // 0: rel0, 1: rel1
    const int c8   = (l & 15) * 8;

    int dr = cnt[(size_t)half * N + wv];
    int d  = dr < CAP ? dr : CAP;
    float inv = dr > 0 ? 1.f / (float)dr : 0.f;
    const int* lst = elist + ((size_t)half * N + wv) * CAP;

    float acc[8];
#pragma unroll
    for (int j = 0; j < 8; j++) acc[j] = 0.f;

    const f16x8 zv = {};
    for (int p = e2; p < d; p += 8) {
        int p1 = p + 2, p2 = p + 4, p3 = p + 6;
        int s0 = lst[p];
        f16x8 v0 = *(const f16x8*)&X[(size_t)s0 * ldx + c8];
        f16x8 v1 = zv, v2 = zv, v3 = zv;
        if (p1 < d) { int s = lst[p1]; v1 = *(const f16x8*)&X[(size_t)s * ldx + c8]; }
        if (p2 < d) { int s = lst[p2]; v2 = *(const f16x8*)&X[(size_t)s * ldx + c8]; }
        if (p3 < d) { int s = lst[p3]; v3 = *(const f16x8*)&X[(size_t)s * ldx + c8]; }
#pragma unroll
        for (int j = 0; j < 8; j++)
            acc[j] += (float)v0[j] + (float)v1[j] + (float)v2[j] + (float)v3[j];
    }

    // merge the two slot copies within each half (convergent), apply mean scale
#pragma unroll
    for (int j = 0; j < 8; j++) {
        acc[j] += __shfl_xor(acc[j], 16);
        acc[j] *= inv;
    }

    if (MODE == 0) {
        if (eo == 0) {                       // m0 -> cols 128..255
            f16x8 o;
#pragma unroll
            for (int j = 0; j < 8; j++) o[j] = (_Float16)acc[j];
            *(f16x8*)&Mout[(size_t)wv * 384 + 128 + c8] = o;
        } else if (eo == 2) {                // m1 -> cols 256..383
            f16x8 o;
#pragma unroll
            for (int j = 0; j < 8; j++) o[j] = (_Float16)acc[j];
            *(f16x8*)&Mout[(size_t)wv * 384 + 256 + c8] = o;
        }
    } else {
        // fused projection: eo==0 -> rel0 part, eo==2 -> rel1 part,
        // eo==1 -> x[dst] part, eo==3 idle. OUT==3 hard-coded.
        float p0 = 0.f, p1 = 0.f, p2 = 0.f;
        if (eo == 1) {
            f16x8 xv = *(const f16x8*)&X[(size_t)wv * ldx + c8];
#pragma unroll
            for (int j = 0; j < 8; j++) {
                float xf = (float)xv[j];
                const float* wr = wfin + (size_t)(c8 + j) * 3;
                p0 += xf * wr[0]; p1 += xf * wr[1]; p2 += xf * wr[2];
            }
        } else if (eo == 0 || eo == 2) {
            const float* wb = wfin + (size_t)(eo == 0 ? 1 : 2) * H * 3;
#pragma unroll
            for (int j = 0; j < 8; j++) {
                const float* wr = wb + (size_t)(c8 + j) * 3;
                p0 += acc[j] * wr[0]; p1 += acc[j] * wr[1]; p2 += acc[j] * wr[2];
            }
        }
        // convergent full-wave reduction
#pragma unroll
        for (int off = 1; off <= 32; off <<= 1) {
            p0 += __shfl_xor(p0, off);
            p1 += __shfl_xor(p1, off);
            p2 += __shfl_xor(p2, off);
        }
        if (l == 0) {
            out[(size_t)wv * 3 + 0] = p0 + bfin[0];
            out[(size_t)wv * 3 + 1] = p1 + bfin[1];
            out[(size_t)wv * 3 + 2] = p2 + bfin[2];
        }
    }
}

// ---------------- concat GEMM: x2 = [x|m0|m1] @ Wcat + b_conv (K=384) -------------
// gemm3 structure (proven): 512 thr = 8 waves x 16 cols, grid-stride 16-row
// tiles, B fully in regs (12 frags = 48 VGPR), next tile's x prefetched.
__global__ __launch_bounds__(512) void gemm_cat(const _Float16* __restrict__ XC,
    const _Float16* __restrict__ WT, const float* __restrict__ bias,
    _Float16* __restrict__ X2, int M, int mtiles, int ldc)
{
    const int w   = threadIdx.x >> 6;
    const int l   = threadIdx.x & 63;
    const int l15 = l & 15;
    const int q   = l >> 4;
    const int col = w * 16 + l15;

    f16x8 bf[12];
    {
        const _Float16* wpp = WT + (size_t)col * 384 + q * 8;
#pragma unroll
        for (int c = 0; c < 12; c++) bf[c] = *(const f16x8*)(wpp + c * 32);
    }
    const float bj = bias[col];

    int t = blockIdx.x;
    if (t >= mtiles) return;
    f16x8 xf[12];
    {
        const _Float16* xp = XC + ((size_t)t * 16 + l15) * 384 + q * 8;
#pragma unroll
        for (int c = 0; c < 12; c++) xf[c] = *(const f16x8*)(xp + c * 32);
    }

    const f32x4 z4 = {0.f, 0.f, 0.f, 0.f};
    while (true) {
        int tn = t + gridDim.x;
        bool more = tn < mtiles;
        f16x8 xnf[12];
        if (more) {
            const _Float16* xp = XC + ((size_t)tn * 16 + l15) * 384 + q * 8;
#pragma unroll
            for (int c = 0; c < 12; c++) xnf[c] = *(const f16x8*)(xp + c * 32);
        }

        f32x4 a0 = z4;
#pragma unroll
        for (int c = 0; c < 12; c++)
            a0 = __builtin_amdgcn_mfma_f32_16x16x32_f16(xf[c], bf[c], a0, 0, 0, 0);

#pragma unroll
        for (int rg = 0; rg < 4; rg++) {
            int row = t * 16 + q * 4 + rg;
            if (row < M) X2[(size_t)row * ldc + col] = (_Float16)(a0[rg] + bj);
        }
        if (!more) break;
        t = tn;
#pragma unroll
        for (int c = 0; c < 12; c++) xf[c] = xnf[c];
    }
}

// ---------------- generic projection fallback (OUT != 3) -------------------------
__global__ __launch_bounds__(256) void proj_generic(const _Float16* __restrict__ XC,
    const float* __restrict__ wfin, const float* __restrict__ bfin,
    float* __restrict__ out, int N, int OUT)
{
    int row = blockIdx.x * 4 + (threadIdx.x >> 6);
    int l = threadIdx.x & 63;
    if (row >= N) return;
    float xv[6];
#pragma unroll
    for (int i = 0; i < 6; i++) xv[i] = (float)XC[(size_t)row * 384 + l * 6 + i];
    for (int c = 0; c < OUT; c++) {
        float p = 0.f;
#pragma unroll
        for (int i = 0; i < 6; i++) p += xv[i] * wfin[(size_t)(l * 6 + i) * OUT + c];
        for (int off = 32; off > 0; off >>= 1) p += __shfl_down(p, off);
        if (l == 0) out[(size_t)row * OUT + c] = p + bfin[c];
    }
}

extern "C" void kernel_launch(void* const* d_in, const int* in_sizes, int n_in,
                              void* d_out, int out_size, void* d_ws, size_t ws_size,
                              hipStream_t stream) {
    const float* feature = (const float*)d_in[0];
    const int*   ei      = (const int*)d_in[1];   // [2,E]: src then dst
    const int*   et      = (const int*)d_in[2];   // [E]
    const float* w_in    = (const float*)d_in[3];
    const float* b_in    = (const float*)d_in[4];
    const float* w_rel   = (const float*)d_in[5];
    const float* w_root  = (const float*)d_in[6];
    const float* b_conv  = (const float*)d_in[7];
    const float* w_out   = (const float*)d_in[8];
    const float* b_out   = (const float*)d_in[9];

    const int HH   = in_sizes[4];                 // 128
    const int D_IN = in_sizes[3] / HH;            // 768
    const int N    = in_sizes[0] / D_IN;          // 50000
    const int E    = in_sizes[1] / 2;             // 600000
    const int OUT  = in_sizes[9];                 // 3

    // workspace layout (16B-aligned segments)
    char* base = (char*)d_ws;
    _Float16* wInT  = (_Float16*)base;                             // 768*128 packed
    _Float16* wcatT = wInT + (size_t)D_IN * HH;                    // 128*384
    _Float16* xc1   = wcatT + (size_t)HH * 384;                    // N*384 [x|m0|m1]
    _Float16* xc2   = xc1 + (size_t)N * 384;                       // N*384 (fused: N*128 used)
    float* wfin     = (float*)(xc2 + (size_t)N * 384);             // 3*128*OUT
    float* bfin     = wfin + (size_t)3 * HH * (OUT > 0 ? OUT : 1); // OUT
    int* cnt        = (int*)(bfin + ((OUT + 3) & ~3));             // 2N
    int* elist      = cnt + (size_t)2 * N;                         // 2N*CAP

    hipMemsetAsync(cnt, 0, sizeof(int) * (size_t)2 * N, stream);
    prep_w<<<(D_IN * HH + HH * 384 + 255) / 256, 256, 0, stream>>>(
        w_in, w_root, w_rel, wInT, wcatT, D_IN);
    prep_fin<<<2, 256, 0, stream>>>(w_root, w_rel, b_conv, w_out, b_out,
                                    wfin, bfin, OUT);
    hist_fill<<<(E + 255) / 256, 256, 0, stream>>>(ei, ei + E, et, cnt, elist, E, N);

    // x1 = fp16(leakyrelu(feature @ w_in + b_in)) -> xc1[:,0:128]
    gemm_big<<<(N + 63) / 64, 256, 0, stream>>>(feature, wInT, b_in, xc1, N, D_IN, 384);

    const int mtiles  = (N + 15) / 16;
    const int gblocks = (N + 3) / 4;

    // layer 1: gather raw x means, then one K=384 GEMM
    gather_k<0><<<gblocks, 256, 0, stream>>>(xc1, 384, xc1, elist, cnt, N,
                                             nullptr, nullptr, nullptr);
    if (OUT == 3) {
        // x2 packed [N,128]; layer 2 + output projection fused into the gather
        gemm_cat<<<1024, 512, 0, stream>>>(xc1, wcatT, b_conv, xc2, N, mtiles, 128);
        gather_k<1><<<gblocks, 256, 0, stream>>>(xc2, 128, nullptr, elist, cnt, N,
                                                 wfin, bfin, (float*)d_out);
    } else {
        // generic fallback: build [x2|m0|m1] then project with Wfin [384,OUT]
        gemm_cat<<<1024, 512, 0, stream>>>(xc1, wcatT, b_conv, xc2, N, mtiles, 384);
        gather_k<0><<<gblocks, 256, 0, stream>>>(xc2, 384, xc2, elist, cnt, N,
                                                 nullptr, nullptr, nullptr);
        proj_generic<<<gblocks, 256, 0, stream>>>(xc2, wfin, bfin, (float*)d_out, N, OUT);
    }
}